// Round 1
// baseline (454.549 us; speedup 1.0000x reference)
//
#include <hip/hip_runtime.h>

typedef unsigned short u16;
typedef unsigned int u32;
typedef __attribute__((ext_vector_type(8))) short bfrag_t;   // 8 bf16 (4 VGPRs)
typedef __attribute__((ext_vector_type(4))) float accfrag_t; // 4 fp32

// ---------- bf16 helpers (RNE) ----------
__device__ __forceinline__ u16 f2b(float f) {
    u32 u = __float_as_uint(f);
    u32 r = (u + 0x7FFFu + ((u >> 16) & 1u)) >> 16;
    return (u16)r;
}
__device__ __forceinline__ float b2f(u16 b) {
    return __uint_as_float(((u32)b) << 16);
}

// ---------- async global->LDS, 16B per lane ----------
__device__ __forceinline__ void load16(const u16* g, u16* l) {
    __builtin_amdgcn_global_load_lds(
        (__attribute__((address_space(1))) void*)(u16*)g,
        (__attribute__((address_space(3))) void*)l,
        16, 0, 0);
}

// ---------- weight transpose + bf16 convert: in[K,N] f32 -> out[N,K] bf16 ----------
__global__ void k_transpose_bf16(const float* __restrict__ in, u16* __restrict__ out,
                                 int K, int N) {
    int idx = blockIdx.x * blockDim.x + threadIdx.x;
    if (idx >= K * N) return;
    int n = idx / K;
    int k = idx - n * K;
    out[idx] = f2b(in[k * N + n]);
}

// ---------- unfold: x[8,256,56,56] f32 -> t[25088,2304] bf16 ----------
// l = b*3136 + h*56 + w ; d = c*9 + ki*3 + kj
__global__ void k_unfold(const float* __restrict__ x, u16* __restrict__ t) {
    const int l = blockIdx.x;
    const int b = l / 3136;
    const int rem = l - b * 3136;
    const int h = rem / 56;
    const int w = rem - h * 56;
    const int tid = threadIdx.x;
    u16* trow = t + (size_t)l * 2304;
    const float* xb = x + (size_t)b * 256 * 3136;
#pragma unroll
    for (int kk = 0; kk < 9; ++kk) {
        int d = tid + kk * 256;
        int c = d / 9;
        int r = d - c * 9;
        int ki = r / 3;
        int kj = r - ki * 3;
        int hh = h + ki - 1;
        int ww = w + kj - 1;
        float v = 0.f;
        if ((unsigned)hh < 56u && (unsigned)ww < 56u)
            v = xb[c * 3136 + hh * 56 + ww];
        trow[d] = f2b(v);
    }
}

// ---------- GEMM: C[M,N] = A[M,K] * Bt[N,K]^T, fused epilogues ----------
enum { EPI_RELU = 0, EPI_SIGMUL = 1, EPI_BIAS = 2 };

template <int EPI>
__global__ __launch_bounds__(256) void k_gemm(
    const u16* __restrict__ A, const u16* __restrict__ Bt,
    const float* __restrict__ bias,
    u16* __restrict__ outB,    // EPI_RELU: bf16 out (h1)
    u16* __restrict__ tmul,    // EPI_SIGMUL: in-place t *= sigmoid(acc+bias)
    float* __restrict__ outF,  // EPI_BIAS: f32 out
    int M, int N, int K) {
    __shared__ __align__(16) u16 As[128 * 32];
    __shared__ __align__(16) u16 Bs[128 * 32];
    const int tid = threadIdx.x;
    const int wave = tid >> 6;
    const int lane = tid & 63;
    const int wm = wave >> 1;   // 2x2 wave grid over 128x128 tile
    const int wn = wave & 1;
    const int tm = blockIdx.y;
    const int tn = blockIdx.x;

    // staging: per wave, 2 calls of 64 lanes x 16B for A and B each.
    // call q covers rows wave*32 + q*16 + lane/4, cols (lane&3)*8 .. +8
    const int srow = lane >> 2;        // 0..15
    const int scol = (lane & 3) * 8;   // 0,8,16,24
    const u16* gA0 = A + ((size_t)tm * 128 + wave * 32 + srow) * K + scol;
    const u16* gA1 = gA0 + (size_t)16 * K;
    const u16* gB0 = Bt + ((size_t)tn * 128 + wave * 32 + srow) * K + scol;
    const u16* gB1 = gB0 + (size_t)16 * K;
    u16* lA0 = As + wave * 1024;
    u16* lA1 = As + wave * 1024 + 512;
    u16* lB0 = Bs + wave * 1024;
    u16* lB1 = Bs + wave * 1024 + 512;

    accfrag_t acc[4][4];
#pragma unroll
    for (int i = 0; i < 4; ++i)
#pragma unroll
        for (int j = 0; j < 4; ++j) acc[i][j] = (accfrag_t)0.f;

    const int fr = lane & 15;  // frag row (A m / B n) and D col
    const int fq = lane >> 4;  // quad

    for (int kt = 0; kt < K; kt += 32) {
        __syncthreads();  // previous tile fully consumed
        load16(gA0, lA0);
        load16(gA1, lA1);
        load16(gB0, lB0);
        load16(gB1, lB1);
        gA0 += 32; gA1 += 32; gB0 += 32; gB1 += 32;
        __syncthreads();  // drains vmcnt incl. global_load_lds

        bfrag_t af[4], bf[4];
#pragma unroll
        for (int i = 0; i < 4; ++i)
            af[i] = *(const bfrag_t*)(As + (wm * 64 + i * 16 + fr) * 32 + fq * 8);
#pragma unroll
        for (int j = 0; j < 4; ++j)
            bf[j] = *(const bfrag_t*)(Bs + (wn * 64 + j * 16 + fr) * 32 + fq * 8);
#pragma unroll
        for (int i = 0; i < 4; ++i)
#pragma unroll
            for (int j = 0; j < 4; ++j)
                acc[i][j] = __builtin_amdgcn_mfma_f32_16x16x32_bf16(af[i], bf[j],
                                                                    acc[i][j], 0, 0, 0);
    }

    // epilogue: D col = lane&15, row = quad*4 + reg   [verified m89/m91]
    const size_t rowBase = (size_t)tm * 128 + wm * 64;
    const int colBase = tn * 128 + wn * 64;
#pragma unroll
    for (int i = 0; i < 4; ++i) {
#pragma unroll
        for (int j = 0; j < 4; ++j) {
            const int col = colBase + j * 16 + fr;
            const float bv = bias[col];
#pragma unroll
            for (int r = 0; r < 4; ++r) {
                const size_t row = rowBase + i * 16 + fq * 4 + r;
                const float v = acc[i][j][r] + bv;
                if (EPI == EPI_RELU) {
                    outB[row * (size_t)N + col] = f2b(v > 0.f ? v : 0.f);
                } else if (EPI == EPI_SIGMUL) {
                    const size_t idx = row * (size_t)N + col;
                    const float s = 1.f / (1.f + __expf(-v));
                    tmul[idx] = f2b(b2f(tmul[idx]) * s);
                } else {
                    outF[row * (size_t)N + col] = v;
                }
            }
        }
    }
}

extern "C" void kernel_launch(void* const* d_in, const int* in_sizes, int n_in,
                              void* d_out, int out_size, void* d_ws, size_t ws_size,
                              hipStream_t stream) {
    const float* x  = (const float*)d_in[0];
    const float* W1 = (const float*)d_in[1];
    const float* b1 = (const float*)d_in[2];
    const float* W2 = (const float*)d_in[3];
    const float* b2 = (const float*)d_in[4];
    const float* W3 = (const float*)d_in[5];
    const float* b3 = (const float*)d_in[6];
    float* out = (float*)d_out;

    const size_t L = 25088, D = 2304, C = 256;
    char* ws = (char*)d_ws;
    u16* t   = (u16*)ws; ws += L * D * 2;   // 115.6 MB
    u16* h1  = (u16*)ws; ws += L * C * 2;   // 12.8 MB
    u16* W1t = (u16*)ws; ws += D * C * 2;
    u16* W2t = (u16*)ws; ws += D * C * 2;
    u16* W3t = (u16*)ws; ws += D * C * 2;

    const int nt = (int)(D * C);
    k_transpose_bf16<<<(nt + 255) / 256, 256, 0, stream>>>(W1, W1t, 2304, 256);
    k_transpose_bf16<<<(nt + 255) / 256, 256, 0, stream>>>(W2, W2t, 256, 2304);
    k_transpose_bf16<<<(nt + 255) / 256, 256, 0, stream>>>(W3, W3t, 2304, 256);
    k_unfold<<<25088, 256, 0, stream>>>(x, t);

    // GEMM1: h1 = relu(t @ W1 + b1)            M=25088 N=256  K=2304
    k_gemm<EPI_RELU><<<dim3(2, 196), 256, 0, stream>>>(
        t, W1t, b1, h1, nullptr, nullptr, 25088, 256, 2304);
    // GEMM2: t *= sigmoid(h1 @ W2 + b2)        M=25088 N=2304 K=256  (in-place on t)
    k_gemm<EPI_SIGMUL><<<dim3(18, 196), 256, 0, stream>>>(
        h1, W2t, b2, nullptr, t, nullptr, 25088, 2304, 256);
    // GEMM3: out = (t*s) @ W3 + b3             M=25088 N=256  K=2304
    k_gemm<EPI_BIAS><<<dim3(2, 196), 256, 0, stream>>>(
        t, W3t, b3, nullptr, nullptr, out, 25088, 256, 2304);
}

// Round 2
// 307.546 us; speedup vs baseline: 1.4780x; 1.4780x over previous
//
#include <hip/hip_runtime.h>

typedef unsigned short u16;
typedef unsigned int u32;
typedef __attribute__((ext_vector_type(8))) short bfrag_t;   // 8 bf16 (4 VGPRs)
typedef __attribute__((ext_vector_type(4))) float accfrag_t; // 4 fp32

// ---------- bf16 helpers (RNE) ----------
__device__ __forceinline__ u16 f2b(float f) {
    u32 u = __float_as_uint(f);
    u32 r = (u + 0x7FFFu + ((u >> 16) & 1u)) >> 16;
    return (u16)r;
}
__device__ __forceinline__ float b2f(u16 b) {
    return __uint_as_float(((u32)b) << 16);
}

// ---------- async global->LDS, 16B per lane ----------
__device__ __forceinline__ void load16(const u16* g, u16* l) {
    __builtin_amdgcn_global_load_lds(
        (__attribute__((address_space(1))) void*)(u16*)g,
        (__attribute__((address_space(3))) void*)l,
        16, 0, 0);
}

// ============================================================
// x[8,256,56,56] f32 -> x_tp[8,58,58,256] bf16, zero-padded border.
// x_tp[b][h'][w'][c] = x[b][c][h'-1][w'-1] (0 outside)
// ============================================================
__global__ __launch_bounds__(256) void k_xtp(const float* __restrict__ x,
                                             u16* __restrict__ xtp) {
    const int bh = blockIdx.x;          // 8*58
    const int b = bh / 58;
    const int hp = bh - b * 58;
    const int tid = threadIdx.x;
    u16* rowbase = xtp + (size_t)(b * 58 + hp) * 58 * 256;
    if (hp == 0 || hp == 57) {
        u32* p = (u32*)rowbase;
        for (int i = tid; i < 58 * 128; i += 256) p[i] = 0;
        return;
    }
    __shared__ float lds[256 * 57];     // stride 57 -> conflict-free column reads
    const int h = hp - 1;
    const float* xb = x + (size_t)b * 802816 + h * 56;
    for (int idx = tid; idx < 256 * 56; idx += 256) {
        int c = idx / 56;
        int w = idx - c * 56;
        lds[c * 57 + w] = xb[c * 3136 + w];
    }
    __syncthreads();
    rowbase[tid] = 0;                   // w'=0 pad
    rowbase[57 * 256 + tid] = 0;        // w'=57 pad
    for (int wp = 1; wp <= 56; ++wp)
        rowbase[wp * 256 + tid] = f2b(lds[tid * 57 + (wp - 1)]);
}

// ============================================================
// Weight prep. K-permutation: d' = rr*256 + c  <->  d = c*9 + rr
// ============================================================
__global__ void k_wt(const float* __restrict__ in, u16* __restrict__ out) {
    // in = W [2304, 256]; out[n][k'] = in[map(k')][n]   (256 x 2304)
    int idx = blockIdx.x * 256 + threadIdx.x;   // 256*2304
    int n = idx / 2304;
    int kp = idx - n * 2304;
    int d = (kp & 255) * 9 + (kp >> 8);
    out[idx] = f2b(in[d * 256 + n]);
}
__global__ void k_w2t(const float* __restrict__ in, u16* __restrict__ out) {
    // in = W2 [256, 2304]; out[n'][k] = in[k][map(n')]  (2304 x 256)
    int idx = blockIdx.x * 256 + threadIdx.x;   // 2304*256
    int np = idx >> 8;
    int k = idx & 255;
    int d = (np & 255) * 9 + (np >> 8);
    out[idx] = f2b(in[k * 2304 + d]);
}
__global__ void k_b2p(const float* __restrict__ in, float* __restrict__ out) {
    int idx = blockIdx.x * 256 + threadIdx.x;
    if (idx < 2304) out[idx] = in[(idx & 255) * 9 + (idx >> 8)];
}

// ============================================================
// Tall-K GEMM (K=2304, N=256 global), tile M=64 x N=128, 4 waves (2x2),
// wave-tile 32x64. IMPL=true: A gathered implicitly from x_tp (GEMM1).
// EPI 0: relu -> bf16 (h1). EPI 1: +bias -> f32 (out).
// ============================================================
template <bool IMPL, int EPI>
__global__ __launch_bounds__(256) void k_gemm_tk(
    const u16* __restrict__ Asrc,   // IMPL: x_tp ; else u [25088,2304]
    const u16* __restrict__ Bt,     // [256, 2304] (k'-order)
    const float* __restrict__ bias, // [256]
    u16* __restrict__ outB, float* __restrict__ outF) {
    __shared__ __align__(16) u16 As[64 * 32];
    __shared__ __align__(16) u16 Bs[128 * 32];
    const int tid = threadIdx.x;
    const int wave = tid >> 6;
    const int lane = tid & 63;
    const int tn = blockIdx.x;      // 0..1
    const int tm = blockIdx.y;      // 0..391
    const int srow = lane >> 2;     // 0..15
    const int scol = (lane & 3) * 8;

    // per-thread staged A row (1 row): wave*16 + srow
    int aoff;
    {
        int l = tm * 64 + wave * 16 + srow;
        if (IMPL) {
            int b = l / 3136;
            int rem = l - b * 3136;
            int h = rem / 56;
            int w = rem - h * 56;
            aoff = ((b * 58 + h + 1) * 58 + (w + 1)) * 256 + scol;
        } else {
            aoff = l * 2304 + scol;   // < 2^27, fits int
        }
    }
    const u16* gB0 = Bt + (size_t)(tn * 128 + wave * 32 + srow) * 2304 + scol;
    const u16* gB1 = gB0 + (size_t)16 * 2304;
    u16* lA = As + wave * 512 + lane * 8;
    u16* lB0 = Bs + wave * 1024 + lane * 8;
    u16* lB1 = lB0 + 512;

    accfrag_t acc[2][4];
#pragma unroll
    for (int i = 0; i < 2; ++i)
#pragma unroll
        for (int j = 0; j < 4; ++j) acc[i][j] = (accfrag_t)0.f;

    const int fr = lane & 15;
    const int fq = lane >> 4;
    const int wm = wave >> 1;
    const int wn = wave & 1;

    int kp = 0;
    for (int rr = 0; rr < 9; ++rr) {
        const int shift = IMPL ? ((rr / 3 - 1) * 58 + (rr % 3 - 1)) * 256 : 0;
#pragma unroll
        for (int c0 = 0; c0 < 256; c0 += 32) {
            __syncthreads();
            const u16* ga = IMPL ? (Asrc + aoff + shift + c0)
                                 : (Asrc + aoff + kp + c0);
            load16(ga, lA);
            load16(gB0 + kp + c0, lB0);
            load16(gB1 + kp + c0, lB1);
            __syncthreads();
            bfrag_t af[2], bf[4];
#pragma unroll
            for (int i = 0; i < 2; ++i)
                af[i] = *(const bfrag_t*)(As + (wm * 32 + i * 16 + fr) * 32 + fq * 8);
#pragma unroll
            for (int j = 0; j < 4; ++j)
                bf[j] = *(const bfrag_t*)(Bs + (wn * 64 + j * 16 + fr) * 32 + fq * 8);
#pragma unroll
            for (int i = 0; i < 2; ++i)
#pragma unroll
                for (int j = 0; j < 4; ++j)
                    acc[i][j] = __builtin_amdgcn_mfma_f32_16x16x32_bf16(
                        af[i], bf[j], acc[i][j], 0, 0, 0);
        }
        kp += 256;
    }

    // epilogue: D col = lane&15, row = quad*4 + reg
    const int l0 = tm * 64;
    const int colBase = tn * 128 + wn * 64;
#pragma unroll
    for (int i = 0; i < 2; ++i) {
#pragma unroll
        for (int j = 0; j < 4; ++j) {
            const int col = colBase + j * 16 + fr;
            const float bv = bias[col];
#pragma unroll
            for (int r = 0; r < 4; ++r) {
                const int row = l0 + wm * 32 + i * 16 + fq * 4 + r;
                const float v = acc[i][j][r] + bv;
                if (EPI == 0)
                    outB[(size_t)row * 256 + col] = f2b(v > 0.f ? v : 0.f);
                else
                    outF[(size_t)row * 256 + col] = v;
            }
        }
    }
}

// ============================================================
// GEMM2: logits = h1 @ W2t' + b2' (M=25088, N=2304, K=256), tile 128x128.
// Epilogue: u[l][d'] = x_tp-gather(l,d') * sigmoid(logit), vectorized via LDS.
// ============================================================
__global__ __launch_bounds__(256) void k_gemm2(
    const u16* __restrict__ h1, const u16* __restrict__ W2t,
    const float* __restrict__ b2p, const u16* __restrict__ xtp,
    u16* __restrict__ u) {
    __shared__ __align__(16) u16 buf[16384];  // 32KB: staging then logit tile
    u16* As = buf;
    u16* Bs = buf + 4096;
    const int tid = threadIdx.x;
    const int wave = tid >> 6;
    const int lane = tid & 63;
    const int tn = blockIdx.x;   // 0..17
    const int tm = blockIdx.y;   // 0..195
    const int srow = lane >> 2;
    const int scol = (lane & 3) * 8;

    const u16* gA0 = h1 + (size_t)(tm * 128 + wave * 32 + srow) * 256 + scol;
    const u16* gA1 = gA0 + 16 * 256;
    const u16* gB0 = W2t + (size_t)(tn * 128 + wave * 32 + srow) * 256 + scol;
    const u16* gB1 = gB0 + 16 * 256;
    u16* lA0 = As + wave * 1024 + lane * 8;
    u16* lA1 = lA0 + 512;
    u16* lB0 = Bs + wave * 1024 + lane * 8;
    u16* lB1 = lB0 + 512;

    accfrag_t acc[4][4];
#pragma unroll
    for (int i = 0; i < 4; ++i)
#pragma unroll
        for (int j = 0; j < 4; ++j) acc[i][j] = (accfrag_t)0.f;

    const int fr = lane & 15;
    const int fq = lane >> 4;
    const int wm = wave >> 1;
    const int wn = wave & 1;

#pragma unroll
    for (int k0 = 0; k0 < 256; k0 += 32) {
        __syncthreads();
        load16(gA0 + k0, lA0);
        load16(gA1 + k0, lA1);
        load16(gB0 + k0, lB0);
        load16(gB1 + k0, lB1);
        __syncthreads();
        bfrag_t af[4], bf[4];
#pragma unroll
        for (int i = 0; i < 4; ++i)
            af[i] = *(const bfrag_t*)(As + (wm * 64 + i * 16 + fr) * 32 + fq * 8);
#pragma unroll
        for (int j = 0; j < 4; ++j)
            bf[j] = *(const bfrag_t*)(Bs + (wn * 64 + j * 16 + fr) * 32 + fq * 8);
#pragma unroll
        for (int i = 0; i < 4; ++i)
#pragma unroll
            for (int j = 0; j < 4; ++j)
                acc[i][j] = __builtin_amdgcn_mfma_f32_16x16x32_bf16(
                    af[i], bf[j], acc[i][j], 0, 0, 0);
    }

    __syncthreads();  // staging LDS dead; safe to repurpose as logit tile
    // store logits z = acc + b2' as bf16 in C-layout
#pragma unroll
    for (int i = 0; i < 4; ++i) {
#pragma unroll
        for (int j = 0; j < 4; ++j) {
            const int coll = wn * 64 + j * 16 + fr;
            const float bv = b2p[tn * 128 + coll];
#pragma unroll
            for (int r = 0; r < 4; ++r) {
                const int rowl = wm * 64 + i * 16 + fq * 4 + r;
                buf[rowl * 128 + coll] = f2b(acc[i][j][r] + bv);
            }
        }
    }
    __syncthreads();

    // vectorized gather-multiply-store: 8 x (16B LDS read + 16B x_tp read + 16B store)
    const int l0 = tm * 128;
    const int rrB = tn >> 1;  // rr uniform per block (128-tiles nest in 256-blocks)
    const int shift = ((rrB / 3 - 1) * 58 + (rrB % 3 - 1)) * 256;
    const int cbase = (tn & 1) * 128;
#pragma unroll
    for (int it = 0; it < 8; ++it) {
        const int chunk = it * 256 + tid;
        const int rowl = chunk >> 4;
        const int c8 = (chunk & 15) * 8;
        const int l = l0 + rowl;
        const int b = l / 3136;
        const int rem = l - b * 3136;
        const int h = rem / 56;
        const int w = rem - h * 56;
        const int xoff = ((b * 58 + h + 1) * 58 + (w + 1)) * 256 + shift + cbase + c8;
        bfrag_t zv = *(const bfrag_t*)(buf + rowl * 128 + c8);
        bfrag_t xv = *(const bfrag_t*)(xtp + xoff);
        bfrag_t rv;
#pragma unroll
        for (int e = 0; e < 8; ++e) {
            const float z = b2f((u16)zv[e]);
            const float s = 1.f / (1.f + __expf(-z));
            rv[e] = (short)f2b(b2f((u16)xv[e]) * s);
        }
        *(bfrag_t*)(u + (size_t)l * 2304 + tn * 128 + c8) = rv;
    }
}

extern "C" void kernel_launch(void* const* d_in, const int* in_sizes, int n_in,
                              void* d_out, int out_size, void* d_ws, size_t ws_size,
                              hipStream_t stream) {
    const float* x  = (const float*)d_in[0];
    const float* W1 = (const float*)d_in[1];
    const float* b1 = (const float*)d_in[2];
    const float* W2 = (const float*)d_in[3];
    const float* b2 = (const float*)d_in[4];
    const float* W3 = (const float*)d_in[5];
    const float* b3 = (const float*)d_in[6];
    float* out = (float*)d_out;

    // ws: u (115.6MB) + x_tp (13.8MB) + W3t (1.18MB) = 130.6MB
    char* ws = (char*)d_ws;
    u16* u_   = (u16*)ws;               ws += (size_t)25088 * 2304 * 2;
    u16* xtp  = (u16*)ws;               ws += (size_t)8 * 58 * 58 * 256 * 2;
    u16* W3t  = (u16*)ws;               ws += (size_t)256 * 2304 * 2;

    // d_out doubles as scratch for tensors dead before GEMM3 (which only
    // writes d_out): h1 (12.85MB) + W1t + W2t + b2p = 15.2MB < 25.7MB
    char* od = (char*)d_out;
    u16* h1    = (u16*)od;
    u16* W1t   = (u16*)(od + 12845056);
    u16* W2t   = (u16*)(od + 14024704);
    float* b2p = (float*)(od + 15204352);

    k_wt<<<2304, 256, 0, stream>>>(W1, W1t);
    k_wt<<<2304, 256, 0, stream>>>(W3, W3t);
    k_w2t<<<2304, 256, 0, stream>>>(W2, W2t);
    k_b2p<<<9, 256, 0, stream>>>(b2, b2p);
    k_xtp<<<464, 256, 0, stream>>>(x, xtp);

    // GEMM1 (implicit conv): h1 = relu(t @ W1 + b1)
    k_gemm_tk<true, 0><<<dim3(2, 392), 256, 0, stream>>>(xtp, W1t, b1, h1, nullptr);
    // GEMM2: u = t * sigmoid(h1 @ W2 + b2)
    k_gemm2<<<dim3(18, 196), 256, 0, stream>>>(h1, W2t, b2p, xtp, u_);
    // GEMM3: out = u @ W3 + b3
    k_gemm_tk<false, 1><<<dim3(2, 392), 256, 0, stream>>>(u_, W3t, b3, nullptr, out);
}